// Round 11
// baseline (193.670 us; speedup 1.0000x reference)
//
#include <hip/hip_runtime.h>
#include <hip/hip_bf16.h>

// MultiHeadAttention: B=2, S=2048, H=16, D=64, E=1024. f32 I/O, bf16 internal.
// R21 vs R20 (186.4us; attn all top-5, Occ 17% vs 50% resident => TAIL: 1024
// blocks = exactly 4/CU all-resident, lengths 1..16 iters, kernel ends at
// depth 1-2 waves/SIMD):
//  * attn: j-split the 8 longest q-tiles (qt>=24) into 2 independent blocks
//    (half the j-tiles each); both write f32 partial O (LDS-staged, full-line
//    f32x4 stores) + lsum into DEAD ws regions (xb: 512x16KB exact; WqkvT:
//    Lpart). attn_combine (256 blocks) merges pairs -> O bf16. Longest block
//    16 -> 12 iters; grid 1280 -> backfill active. Unsplit path = R20 proven
//    barriers verbatim (only epilogue overlay bases moved: Lsc->Ks+17408,
//    Of->Vs base). No new sync structure.
//  * qkv (256x192 8-phase), gemm_out (BK=64), prep: unchanged.

typedef __hip_bfloat16 bf16;
typedef __attribute__((ext_vector_type(8))) short bfrag;    // 8 bf16 = 4 VGPRs
typedef __attribute__((ext_vector_type(4))) float f32x4;
typedef __attribute__((ext_vector_type(16))) float f32x16;  // 32x32 C/D
typedef __attribute__((ext_vector_type(4))) short short4v;

#define MFMA16(a, b, c) __builtin_amdgcn_mfma_f32_16x16x32_bf16(a, b, c, 0, 0, 0)
#define MFMA32(a, b, c) __builtin_amdgcn_mfma_f32_32x32x16_bf16(a, b, c, 0, 0, 0)

__device__ __forceinline__ unsigned pk2(float a, float b) {
  union { __hip_bfloat162 h; unsigned u; } w;
  w.h = __float22bfloat162_rn(make_float2(a, b));
  return w.u;
}

// async global->LDS, 16B per lane; LDS dest = wave-uniform base + lane*16.
__device__ __forceinline__ void gload16(const bf16* g, bf16* l) {
  __builtin_amdgcn_global_load_lds(
      (const __attribute__((address_space(1))) void*)(g),
      (__attribute__((address_space(3))) void*)(l), 16, 0, 0);
}

// raw barrier with compiler memory fences (keep LDS ops from crossing)
__device__ __forceinline__ void barrier_raw() {
  asm volatile("" ::: "memory");
  __builtin_amdgcn_s_barrier();
  asm volatile("" ::: "memory");
}

// ---------------- fused cast + weight transposes --------------------------
// blocks 0..2047: x f32->bf16. 2048..2815: Wq/Wk/Wv -> WqkvT. 2816..3071: Wo.
__global__ __launch_bounds__(256) void prep_all(const float* __restrict__ x,
                                                const float* __restrict__ Wq,
                                                const float* __restrict__ Wk,
                                                const float* __restrict__ Wv,
                                                const float* __restrict__ Wo,
                                                bf16* __restrict__ xb,
                                                bf16* __restrict__ WqkvT,
                                                bf16* __restrict__ WoT) {
  __shared__ bf16 tile[64][80];
  int id = blockIdx.x;
  int t = threadIdx.x;
  if (id < 2048) {
    int i = id * 2048 + t * 8;
    float4 a = *(const float4*)(x + i);
    float4 b = *(const float4*)(x + i + 4);
    union { bf16 h[8]; bfrag v; } tmp;
    tmp.h[0] = __float2bfloat16(a.x); tmp.h[1] = __float2bfloat16(a.y);
    tmp.h[2] = __float2bfloat16(a.z); tmp.h[3] = __float2bfloat16(a.w);
    tmp.h[4] = __float2bfloat16(b.x); tmp.h[5] = __float2bfloat16(b.y);
    tmp.h[6] = __float2bfloat16(b.z); tmp.h[7] = __float2bfloat16(b.w);
    *(bfrag*)(xb + i) = tmp.v;
    return;
  }
  int wid = id - 2048;
  const float* src;
  bf16* dst;
  int srcld, dstld, r0, c0;
  if (wid < 768) {
    int w = wid >> 8, h = (wid >> 4) & 15;
    r0 = (wid & 15) * 64; c0 = 0;
    src = ((w == 0) ? Wq : (w == 1) ? Wk : Wv) + (long)h * 1024 * 64;
    dst = WqkvT + ((long)w * 1024 + h * 64) * 1024;
    srcld = 64; dstld = 1024;
  } else {
    int j = wid - 768;
    c0 = (j & 15) * 64; r0 = (j >> 4) * 64;
    src = Wo; dst = WoT;
    srcld = 1024; dstld = 1024;
  }
  int lr = t >> 3, lc = (t & 7) << 3;
#pragma unroll
  for (int p = 0; p < 2; ++p) {
    int r = lr + p * 32;
    const float* s = src + (long)(r0 + r) * srcld + c0 + lc;
    union { bf16 h8[8]; bfrag v; } tmp;
#pragma unroll
    for (int j = 0; j < 8; ++j) tmp.h8[j] = __float2bfloat16(s[j]);
    *(bfrag*)(&tile[r][lc]) = tmp.v;
  }
  __syncthreads();
#pragma unroll
  for (int p = 0; p < 2; ++p) {
    int c = lr + p * 32;
    union { bf16 h8[8]; bfrag v; } tmp;
#pragma unroll
    for (int j = 0; j < 8; ++j) tmp.h8[j] = tile[lc + j][c];
    *(bfrag*)(dst + (long)(c0 + c) * dstld + r0 + lc) = tmp.v;
  }
}

// ---------------- fused QKV GEMM: 256x192, BK=64, 8-phase counted-vmcnt ---
// (R20-proven.) C[4096][3072] = xb . WT^T. 16x16 = 256 blocks, 512 thr.
__global__ __launch_bounds__(512, 2) void gemm_qkv128(const bf16* __restrict__ xb,
                                                      const bf16* __restrict__ WT,
                                                      const float* __restrict__ bq,
                                                      const float* __restrict__ bk,
                                                      const float* __restrict__ bv,
                                                      bf16* __restrict__ Q,
                                                      bf16* __restrict__ K_,
                                                      bf16* __restrict__ Vt) {
  extern __shared__ bf16 lds[];
  int id = blockIdx.x;
  int xcd = id & 7, idx = id >> 3;
  int tile = xcd * 32 + idx;          // 256 = 16 mt x 16 nt, bijective
  int mt = tile & 15, nt = tile >> 4;
  int m0 = mt * 256, n0 = nt * 192;

  int t = threadIdx.x;
  int wave = t >> 6, lane = t & 63, quad = lane >> 4, col = lane & 15;
  int wm = wave >> 2, wn = wave & 3;

  int schunk = 8 * ((t & 7) ^ ((t >> 3) & 7));   // pre-swizzled source chunk
  const bf16* aSrc = xb + (long)(m0 + (t >> 3)) * 1024 + schunk;
  const bf16* bSrc = WT + (long)(n0 + (t >> 3)) * 1024 + schunk;
  int wv512 = wave * 512;                         // wave-uniform LDS sub-base

  int xoff0 = (quad * 8) ^ ((col & 7) << 3);
  const bf16* aRdB = lds + wm * 8192 + col * 64;
  const bf16* bRdB = lds + 32768 + (wn * 48 + col) * 64;

  f32x4 acc[8][3] = {};

#define STA(BUF, HALF, G, KS)                                                  \
  gload16(aSrc + (long)((HALF)*128 + (G)*64) * 1024 + (KS)*64,                 \
          lds + (BUF)*16384 + (HALF)*8192 + (G)*4096 + wv512)
#define STB(BUF, G, KS)                                                        \
  gload16(bSrc + (long)((G)*64) * 1024 + (KS)*64,                              \
          lds + 32768 + (BUF)*12288 + (G)*4096 + wv512)

#define PHASE(BUF, MH, KC, STAGES, VMW)                                        \
  {                                                                            \
    int xk = xoff0 ^ ((KC)*32);                                                \
    bfrag ra[4], rb[3];                                                        \
    _Pragma("unroll") for (int u = 0; u < 4; ++u)                              \
      ra[u] = *(const bfrag*)(aRdB + (BUF)*16384 + (MH)*4096 + u * 1024 + xk); \
    _Pragma("unroll") for (int c2 = 0; c2 < 3; ++c2)                           \
      rb[c2] = *(const bfrag*)(bRdB + (BUF)*12288 + c2 * 1024 + xk);           \
    STAGES;                                                                    \
    VMW;                                                                       \
    barrier_raw();                                                             \
    __builtin_amdgcn_s_setprio(1);                                             \
    _Pragma("unroll") for (int ni = 0; ni < 3; ++ni)                           \
      _Pragma("unroll") for (int mi2 = 0; mi2 < 4; ++mi2)                      \
        acc[(MH)*4 + mi2][ni] = MFMA16(ra[mi2], rb[ni], acc[(MH)*4 + mi2][ni]);\
    __builtin_amdgcn_s_setprio(0);                                             \
    barrier_raw();                                                             \
  }

#define VM2 asm volatile("s_waitcnt vmcnt(2)" ::: "memory")
#define NOVM

  STA(0, 0, 0, 0); STA(0, 1, 0, 0); STA(0, 0, 1, 0); STA(0, 1, 1, 0);
  STB(0, 0, 0); STB(0, 1, 0); STB(0, 2, 0);
  STA(1, 0, 0, 1); STA(1, 1, 0, 1);
  VM2;
  barrier_raw();

  for (int it = 0; it < 8; ++it) {
    int ksB = 2 * it + 1;
    int kA  = (it < 7) ? 2 * it + 2 : 14;
    int ksB2 = (it < 7) ? 2 * it + 3 : 15;
    PHASE(0, 0, 0, { STA(1, 0, 1, ksB); STA(1, 1, 1, ksB); }, NOVM);   // p1
    PHASE(0, 0, 1, { STB(1, 0, ksB); STB(1, 1, ksB); }, NOVM);         // p2
    PHASE(0, 1, 0, { STB(1, 2, ksB); }, NOVM);                         // p3
    PHASE(0, 1, 1, { STA(0, 0, 0, kA); STA(0, 1, 0, kA); }, VM2);      // p4
    PHASE(1, 0, 0, { STA(0, 0, 1, kA); STA(0, 1, 1, kA); }, NOVM);     // p5
    PHASE(1, 0, 1, { STB(0, 0, kA); STB(0, 1, kA); }, NOVM);           // p6
    PHASE(1, 1, 0, { STB(0, 2, kA); }, NOVM);                          // p7
    PHASE(1, 1, 1, { STA(1, 0, 0, ksB2); STA(1, 1, 0, ksB2); }, VM2);  // p8
  }
#undef PHASE
#undef STA
#undef STB
#undef VM2
#undef NOVM

  asm volatile("s_waitcnt vmcnt(0)" ::: "memory");
  barrier_raw();

  const float SC2 = 0.18033688f;    // (1/8)*log2(e) folded into Q
  int b = m0 >> 11, sbase = m0 & 2047;

  if (n0 < 1920) {
#pragma unroll
    for (int ni = 0; ni < 3; ++ni) {
      int n = wn * 48 + ni * 16 + col;
      int ng = n0 + n;
      int s01 = ng >> 10;
      float bvv = s01 ? bk[ng & 1023] : bq[ng & 1023];
      float qsv = s01 ? 1.0f : SC2;
#pragma unroll
      for (int mi = 0; mi < 8; ++mi) {
        int mrow = wm * 128 + mi * 16 + quad * 4;
#pragma unroll
        for (int r = 0; r < 4; ++r)
          lds[(mrow + r) * 200 + n] = __float2bfloat16((acc[mi][ni][r] + bvv) * qsv);
      }
    }
    barrier_raw();
    int row = t >> 1, half = t & 1;
#pragma unroll
    for (int s = 0; s < 12; ++s) {
      int cl = 96 * half + 8 * s;
      int ng = n0 + cl;
      int s01 = ng >> 10, within = ng & 1023;
      int h = within >> 6, d = within & 63;
      bf16* dst = s01 ? K_ : Q;
      *(bfrag*)(dst + ((long)((b << 4) + h) * 2048 + sbase + row) * 64 + d) =
          *(const bfrag*)(lds + row * 200 + cl);
    }
  } else if (n0 == 1920) {
#pragma unroll
    for (int ni = 0; ni < 3; ++ni) {
      int n = wn * 48 + ni * 16 + col;
      int ng = n0 + n;
      if (ng < 2048) {
        float bvv = bk[ng & 1023];
#pragma unroll
        for (int mi = 0; mi < 8; ++mi) {
          int mrow = wm * 128 + mi * 16 + quad * 4;
#pragma unroll
          for (int r = 0; r < 4; ++r)
            lds[(mrow + r) * 136 + n] = __float2bfloat16(acc[mi][ni][r] + bvv);
        }
      } else {
        int vn = n - 128;
        float bvv = bv[ng & 1023];
#pragma unroll
        for (int mi = 0; mi < 8; ++mi) {
          int m = wm * 128 + mi * 16 + quad * 4;
          union { unsigned u[2]; unsigned long long ull; } pkd;
          pkd.u[0] = pk2(acc[mi][ni][0] + bvv, acc[mi][ni][1] + bvv);
          pkd.u[1] = pk2(acc[mi][ni][2] + bvv, acc[mi][ni][3] + bvv);
          *(unsigned long long*)(lds + 34816 + vn * 264 + m) = pkd.ull;
        }
      }
    }
    barrier_raw();
#pragma unroll
    for (int p = 0; p < 8; ++p) {
      int u = p * 512 + t;
      int row = u >> 4, cl = (u & 15) * 8;
      int within = (n0 + cl) & 1023;
      int h = within >> 6, d = within & 63;
      *(bfrag*)(K_ + ((long)((b << 4) + h) * 2048 + sbase + row) * 64 + d) =
          *(const bfrag*)(lds + row * 136 + cl);
    }
#pragma unroll
    for (int p = 0; p < 4; ++p) {
      int u = p * 512 + t;
      int vn = u >> 5, seg = (u & 31) * 8;
      int within = (n0 + 128 + vn) & 1023;
      int h = within >> 6, d = within & 63;
      *(bfrag*)(Vt + ((long)((b << 4) + h) * 64 + d) * 2048 + sbase + seg) =
          *(const bfrag*)(lds + 34816 + vn * 264 + seg);
    }
  } else {
#pragma unroll
    for (int ni = 0; ni < 3; ++ni) {
      int n = wn * 48 + ni * 16 + col;
      int ng = n0 + n;
      float bvv = bv[ng & 1023];
#pragma unroll
      for (int mi = 0; mi < 8; ++mi) {
        int m = wm * 128 + mi * 16 + quad * 4;
        union { unsigned u[2]; unsigned long long ull; } pkd;
        pkd.u[0] = pk2(acc[mi][ni][0] + bvv, acc[mi][ni][1] + bvv);
        pkd.u[1] = pk2(acc[mi][ni][2] + bvv, acc[mi][ni][3] + bvv);
        *(unsigned long long*)(lds + n * 264 + m) = pkd.ull;
      }
    }
    barrier_raw();
#pragma unroll
    for (int p = 0; p < 12; ++p) {
      int u = p * 512 + t;
      int rn = u >> 5, seg = (u & 31) * 8;
      int within = (n0 + rn) & 1023;
      int h = within >> 6, d = within & 63;
      *(bfrag*)(Vt + ((long)((b << 4) + h) * 64 + d) * 2048 + sbase + seg) =
          *(const bfrag*)(lds + rn * 264 + seg);
    }
  }
}

// ---------------- out-projection: 128x64, BK=64, gload_lds dbuf -----------
__global__ __launch_bounds__(256) void gemm_out(const bf16* __restrict__ O,
                                                const bf16* __restrict__ Bt,
                                                float* __restrict__ Cf) {
  const int K = 1024;
  __shared__ bf16 As[2][128 * 64];
  __shared__ bf16 Bs[2][64 * 64];
  int id = blockIdx.x;
  int xcd = id & 7, sw = id >> 3;
  int m0 = ((xcd << 2) | (sw & 3)) * 128;
  int n0 = (sw >> 2) * 64;
  int t = threadIdx.x;
  int wave = t >> 6, lane = t & 63, quad = lane >> 4, col = lane & 15;
  int wr = (wave >> 1) * 64, wc = (wave & 1) * 32;
  f32x4 acc[2][4] = {};

  int schunk = 8 * ((t & 7) ^ ((t >> 3) & 7));
  int ob = m0 >> 11;
  const bf16* AsrcB = O + (long)ob * 2097152 + (long)((m0 & 2047) + (t >> 3)) * 64 + schunk;
  const bf16* BsrcB = Bt + (long)(n0 + (t >> 3)) * K + schunk;
  int wv = wave * 512;
  int xoff0 = (quad * 8) ^ ((col & 7) << 3);

#define OUT_STAGE(bi, k0n)                                                 \
  {                                                                        \
    long ko = ((long)((k0n) >> 6)) * 131072;                               \
    _Pragma("unroll") for (int i = 0; i < 4; ++i)                          \
      gload16(AsrcB + ko + (long)(32 * i) * 64, &As[bi][i * 2048 + wv]);   \
    _Pragma("unroll") for (int i = 0; i < 2; ++i)                          \
      gload16(BsrcB + (k0n) + (long)(32 * i) * K, &Bs[bi][i * 2048 + wv]); \
  }

  OUT_STAGE(0, 0);
  __syncthreads();
  for (int k0 = 0; k0 < K; k0 += 64) {
    int cur = (k0 >> 6) & 1;
    if (k0 + 64 < K) OUT_STAGE(cur ^ 1, k0 + 64);
#pragma unroll
    for (int kc = 0; kc < 2; ++kc) {
      int xk = xoff0 ^ (kc * 32);
      bfrag ra[4], rb[2];
#pragma unroll
      for (int i = 0; i < 4; ++i)
        ra[i] = *(const bfrag*)(&As[cur][(wr + 16 * i + col) * 64 + xk]);
#pragma unroll
      for (int c = 0; c < 2; ++c)
        rb[c] = *(const bfrag*)(&Bs[cur][(wc + 16 * c + col) * 64 + xk]);
#pragma unroll
      for (int c = 0; c < 2; ++c)
#pragma unroll
        for (int i = 0; i < 4; ++i) acc[c][i] = MFMA16(ra[i], rb[c], acc[c][i]);
    }
    __syncthreads();
  }
#undef OUT_STAGE

#pragma unroll
  for (int c = 0; c < 2; ++c) {
    int n = n0 + wc + 16 * c + col;
#pragma unroll
    for (int i = 0; i < 4; ++i)
#pragma unroll
      for (int r = 0; r < 4; ++r) {
        int m = m0 + wr + 16 * i + quad * 4 + r;
        Cf[(long)m * 1024 + n] = acc[c][i][r];
      }
  }
}

// ---------------- flash attention: S^T dataflow, 2-barrier pipeline -------
// R20 structure. Grid 1280: ids [0,512) = split halves of qt 24..31 (two
// blocks per q-tile: part0 j-tiles [0,nj/2), part1 [nj/2,nj)); ids
// [512,1280) = unsplit qt 23..0. Split blocks write f32 partial O + lsum to
// workspace; attn_combine merges. Unsplit path identical to R20 except
// overlay bases (Lsc in Ks region, Of at Vs base).
__global__ __launch_bounds__(256) void attn_kernel(const bf16* __restrict__ Q,
                                                   const bf16* __restrict__ K_,
                                                   const bf16* __restrict__ Vt,
                                                   bf16* __restrict__ O,
                                                   float* __restrict__ Opart,
                                                   float* __restrict__ Lpart) {
  int id = blockIdx.x;             // 1280 blocks
  int xcd = id & 7;
  int qt, part, isSplit, jj;
  if (id < 512) {                  // longest work first (LPT)
    jj = id >> 3;                  // 0..63
    qt = 31 - (jj >> 3);           // 31..24
    part = (jj >> 2) & 1;
    isSplit = 1;
  } else {
    int u = id - 512;
    jj = u >> 3;                   // 0..95
    qt = 23 - (jj >> 2);           // 23..0
    part = 0;
    isSplit = 0;
  }
  int bh = ((jj & 3) << 3) | xcd;  // 4 bh per XCD

  __shared__ bf16 Ks[128][72];     // [j][d]; epilogue: Osc[64][68]f32 + Lsc
  __shared__ bf16 Vs[64][136];     // [d][j]; epilogue: Of bf16 / Ff f32

  int t = threadIdx.x, wave = t >> 6, lane = t & 63;
  int qh = wave >> 1, jh = wave & 1, hi = lane >> 5, l5 = lane & 31;

  int krow = t >> 3, kg = (t & 7) * 8;
  int vrow = t >> 4, vg = (t & 15) * 8;
  const bf16* KuBase = K_ + (long)bh * 2048 * 64;
  const bf16* VuBase = Vt + (long)bh * 64 * 2048;
  int kL = krow * 64 + kg;         // lane-const
  int vL = vrow * 2048 + vg;       // lane-const

  int q0 = qt * 64;
  int njf = (qt >> 1) + 1;         // full j-tile count for this q-tile
  int b0 = 0, b1 = njf;
  if (isSplit) { int h2 = njf >> 1; b0 = part ? h2 : 0; b1 = part ? njf : h2; }
  int qi = q0 + 32 * qh + l5;      // this lane's global q index

  bfrag qa[4];
  const bf16* qp = Q + ((long)bh * 2048 + q0 + 32 * qh + l5) * 64 + hi * 8;
#pragma unroll
  for (int kd = 0; kd < 4; ++kd) qa[kd] = *(const bfrag*)(qp + kd * 16);

  f32x16 o0, o1;                   // O^T partials: rows d / d+32, col q
  float lsum = 0.f;
#pragma unroll
  for (int r = 0; r < 16; ++r) { o0[r] = 0.f; o1[r] = 0.f; }

  // prefetch j-tile b0 (both K and V)
  bfrag kreg[4], vreg[4];
  {
    const bf16* kp0 = KuBase + (long)(b0 * 128) * 64;
    const bf16* vp0 = VuBase + b0 * 128;
#pragma unroll
    for (int i = 0; i < 4; ++i) {
      kreg[i] = *(const bfrag*)(kp0 + kL + i * 2048);
      vreg[i] = *(const bfrag*)(vp0 + vL + i * 32768);
    }
  }

  for (int jt = b0; jt < b1; ++jt) {
    int j0 = jt * 128;
    __syncthreads();               // prev iter's Ks/Vs reads complete
#pragma unroll
    for (int i = 0; i < 4; ++i) {
      *(bfrag*)(&Ks[krow + 32 * i][kg]) = kreg[i];
      *(bfrag*)(&Vs[vrow + 16 * i][vg]) = vreg[i];
    }
    int jn = (jt + 1 < b1) ? j0 + 128 : j0;       // uniform
    const bf16* kp = KuBase + (long)jn * 64;
    const bf16* vp = VuBase + jn;
#pragma unroll
    for (int i = 0; i < 4; ++i) {
      kreg[i] = *(const bfrag*)(kp + kL + i * 2048);
      vreg[i] = *(const bfrag*)(vp + vL + i * 32768);
    }
    __syncthreads();               // Ks/Vs ready for all waves

    bool lastT = (jt == njf - 1);
    // even qt: last tile's jh==1 half (j in [q0+64,q0+128)) is fully masked.
    if (lastT && jh == 1 && ((qt & 1) == 0)) continue;

    // S^T: per wave 64j (own half) x 32q. A = K rows, B = Q rows.
    f32x16 s0, s1;
#pragma unroll
    for (int r = 0; r < 16; ++r) { s0[r] = 0.f; s1[r] = 0.f; }
    __builtin_amdgcn_s_setprio(1);
#pragma unroll
    for (int kd = 0; kd < 4; ++kd) {
      bfrag ka0 = *(const bfrag*)(&Ks[jh * 64 + l5][kd * 16 + hi * 8]);
      bfrag ka1 = *(const bfrag*)(&Ks[jh * 64 + 32 + l5][kd * 16 + hi * 8]);
      s0 = MFMA32(ka0, qa[kd], s0);
      s1 = MFMA32(ka1, qa[kd], s1);
    }
    __builtin_amdgcn_s_setprio(0);

    // softmax in-register; pack P^T bf16 groups
    unsigned g[2][4][2];
#pragma unroll
    for (int jb = 0; jb < 2; ++jb) {
      float pv[16];
      float ls = 0.f;
#pragma unroll
      for (int r = 0; r < 16; ++r) {
        int jl = (r & 3) + 8 * (r >> 2) + 4 * hi;
        int j = j0 + jh * 64 + jb * 32 + jl;
        float sv = jb ? s1[r] : s0[r];
        float p = __builtin_amdgcn_exp2f(sv);
        if (lastT) p = (j <= qi) ? p : 0.f;
        ls += p;
        pv[r] = p;
      }
      lsum += ls;
#pragma unroll
      for (int gg = 0; gg < 4; ++gg) {
        g[jb][gg][0] = pk2(pv[4 * gg], pv[4 * gg + 1]);
        g[jb][gg][1] = pk2(pv[4 * gg + 2], pv[4 * gg + 3]);
      }
    }

    // PV: O^T += V^T * P^T over own j-half
    __builtin_amdgcn_s_setprio(1);
#pragma unroll
    for (int jb = 0; jb < 2; ++jb) {
#pragma unroll
      for (int c = 0; c < 2; ++c) {
        unsigned a0 = g[jb][2 * c][0], a1 = g[jb][2 * c][1];
        unsigned b0u = g[jb][2 * c + 1][0], b1u = g[jb][2 * c + 1][1];
        asm("v_permlane32_swap_b32 %0, %1" : "+v"(a0), "+v"(b0u));
        asm("v_permlane32_swap_b32 %0, %1" : "+v"(a1), "+v"(b1u));
        union { unsigned u[4]; bfrag f; } pf;
        pf.u[0] = a0;
        pf.u[1] = a1;
        pf.u[2] = b0u;
        pf.u[3] = b1u;
        int kk = jh * 64 + jb * 32 + c * 16 + hi * 8;
        bfrag av0 = *(const bfrag*)(&Vs[l5][kk]);
        bfrag av1 = *(const bfrag*)(&Vs[32 + l5][kk]);
        o0 = MFMA32(av0, pf.f, o0);
        o1 = MFMA32(av1, pf.f, o1);
      }
    }
    __builtin_amdgcn_s_setprio(0);
  }

  // combine hi-halves of lsum (same q, different j-sets)
  lsum += __shfl_xor(lsum, 32, 64);

  __syncthreads();   // all Ks/Vs reads done; overlay scratch
  float* Osc = (float*)&Ks[0][0];                     // [64 q][68 d] (17408B)
  float* Lsc = (float*)((char*)&Ks[0][0] + 17408);    // [64 q] (Ks region 18432B)
  int q = 32 * qh + l5;
  if (jh == 1) {
#pragma unroll
    for (int r = 0; r < 16; ++r) {
      int d = (r & 3) + 8 * (r >> 2) + 4 * hi;
      Osc[q * 68 + d] = o0[r];
      Osc[q * 68 + 32 + d] = o1[r];
    }
    if (hi == 0) Lsc[q] = lsum;
  }
  __syncthreads();

  if (!isSplit) {
    bf16* Of = (bf16*)&Vs[0][0];                      // [64 q][72 d] (9216B)
    if (jh == 0) {
      float inv = 1.f / (lsum + Lsc[q]);
#pragma unroll
      for (int r = 0; r < 16; ++r) {
        int d = (r & 3) + 8 * (r >> 2) + 4 * hi;
        Of[q * 72 + d] = __float2bfloat16((o0[r] + Osc[q * 68 + d]) * inv);
        Of[q * 72 + 32 + d] = __float2bfloat16((o1[r] + Osc[q * 68 + 32 + d]) * inv);
      }
    }
    __syncthreads();
    int row = t >> 2, off = (t & 3) * 16;
    bf16* po = O + ((long)bh * 2048 + q0 + row) * 64 + off;
    *(bfrag*)(po) = *(const bfrag*)(&Of[row * 72 + off]);
    *(bfrag*)(po + 8) = *(const bfrag*)(&Of[row * 72 + off + 8]);
  } else {
    int pidx = (((31 - qt) << 5) | bh) * 2 + part;    // [0,512)
    float* Ff = (float*)&Vs[0][0];                    // [64 q][68 d] f32 (17408B)
    if (jh == 0) {
      float lt = lsum + Lsc[q];
#pragma unroll
      for (int r = 0; r < 16; ++r) {
        int d = (r & 3) + 8 * (r >> 2) + 4 * hi;
        Ff[q * 68 + d] = o0[r] + Osc[q * 68 + d];
        Ff[q * 68 + 32 + d] = o1[r] + Osc[q * 68 + 32 + d];
      }
      if (hi == 0) Lpart[pidx * 64 + q] = lt;
    }
    __syncthreads();
    float* po = Opart + (long)pidx * 4096;
    int row = t >> 2, sg = (t & 3) * 16;
#pragma unroll
    for (int u2 = 0; u2 < 4; ++u2)
      *(float4*)(po + row * 64 + sg + u2 * 4) = *(const float4*)(&Ff[row * 68 + sg + u2 * 4]);
  }
}

// ---------------- combine split attn partials -> O bf16 -------------------
__global__ __launch_bounds__(256) void attn_combine(const float* __restrict__ Opart,
                                                    const float* __restrict__ Lpart,
                                                    bf16* __restrict__ O) {
  int c = blockIdx.x;              // 256 = 8 qt x 32 bh
  int qt = 24 + (c >> 5), bh = c & 31;
  int base = (((31 - qt) << 5) | bh) * 2;
  const float* pa = Opart + (long)base * 4096;
  const float* pb = pa + 4096;
  int t = threadIdx.x;
  int q = t >> 2, sg = (t & 3) * 16;
  float inv = 1.f / (Lpart[base * 64 + q] + Lpart[(base + 1) * 64 + q]);
  union { bf16 h[16]; bfrag v[2]; } o;
#pragma unroll
  for (int u = 0; u < 16; ++u)
    o.h[u] = __float2bfloat16((pa[q * 64 + sg + u] + pb[q * 64 + sg + u]) * inv);
  bf16* po = O + ((long)bh * 2048 + qt * 64 + q) * 64 + sg;
  *(bfrag*)(po) = o.v[0];
  *(bfrag*)(po + 8) = o.v[1];
}

extern "C" void kernel_launch(void* const* d_in, const int* in_sizes, int n_in,
                              void* d_out, int out_size, void* d_ws, size_t ws_size,
                              hipStream_t stream) {
  const float* x  = (const float*)d_in[0];
  const float* Wq = (const float*)d_in[1];
  const float* bq = (const float*)d_in[2];
  const float* Wk = (const float*)d_in[3];
  const float* bk = (const float*)d_in[4];
  const float* Wv = (const float*)d_in[5];
  const float* bv = (const float*)d_in[6];
  const float* Wo = (const float*)d_in[7];
  float* out = (float*)d_out;

  bf16* ws = (bf16*)d_ws;
  const long MB1 = 1 << 20;
  bf16* WqkvT = ws + 0 * MB1;    // [3072][1024]  (dead after qkv -> Lpart)
  bf16* WoT   = ws + 3 * MB1;
  bf16* Q     = ws + 4 * MB1;    // [b][h][s][d]
  bf16* K_    = ws + 8 * MB1;    // [b][h][s][d]
  bf16* Vt    = ws + 12 * MB1;   // [b][h][d][s]
  bf16* O     = ws + 16 * MB1;   // [b][h][s][d]
  bf16* xb    = ws + 20 * MB1;   // (dead after qkv -> Opart: 512 x 16KB = 8MB)

  float* Opart = (float*)xb;     // 512 x [64][64] f32
  float* Lpart = (float*)WqkvT;  // 512 x [64] f32

  prep_all<<<3072, 256, 0, stream>>>(x, Wq, Wk, Wv, Wo, xb, WqkvT, WoT);
  gemm_qkv128<<<256, 512, 114688, stream>>>(xb, WqkvT, bq, bk, bv, Q, K_, Vt);
  attn_kernel<<<1280, 256, 0, stream>>>(Q, K_, Vt, O, Opart, Lpart);
  attn_combine<<<256, 256, 0, stream>>>(Opart, Lpart, O);
  gemm_out<<<512, 256, 0, stream>>>(O, WoT, out);
}

// Round 12
// 187.611 us; speedup vs baseline: 1.0323x; 1.0323x over previous
//
#include <hip/hip_runtime.h>
#include <hip/hip_bf16.h>

// MultiHeadAttention: B=2, S=2048, H=16, D=64, E=1024. f32 I/O, bf16 internal.
// R22 vs R21 (193.7us REGRESSION: j-split raised occ 17->25% with ZERO dur
// change + combine overhead => occupancy is NOT attn's constraint; revert):
//  * attn: R20 4-wave structure restored. THE fix: the two in-loop
//    __syncthreads compile to s_waitcnt vmcnt(0) lgkmcnt(0) + s_barrier,
//    draining the register-targeted prefetch loads EVERY iteration (the m97
//    barrier-drain stall, per-iteration). Staging is reg-based => vmcnt drain
//    is semantically superfluous (VGPRs are private; only ds_writes need
//    lgkm ordering). Replace both with s_waitcnt lgkmcnt(0); s_barrier =>
//    prefetch now truly spans the compute phase. Epilogue barriers unchanged
//    (full drain needed once for the dummy tail prefetch).
//  * qkv (256x192 8-phase), gemm_out (BK=64, gload_lds => drain REQUIRED,
//    untouched), prep: unchanged from R20.

typedef __hip_bfloat16 bf16;
typedef __attribute__((ext_vector_type(8))) short bfrag;    // 8 bf16 = 4 VGPRs
typedef __attribute__((ext_vector_type(4))) float f32x4;
typedef __attribute__((ext_vector_type(16))) float f32x16;  // 32x32 C/D
typedef __attribute__((ext_vector_type(4))) short short4v;

#define MFMA16(a, b, c) __builtin_amdgcn_mfma_f32_16x16x32_bf16(a, b, c, 0, 0, 0)
#define MFMA32(a, b, c) __builtin_amdgcn_mfma_f32_32x32x16_bf16(a, b, c, 0, 0, 0)

__device__ __forceinline__ unsigned pk2(float a, float b) {
  union { __hip_bfloat162 h; unsigned u; } w;
  w.h = __float22bfloat162_rn(make_float2(a, b));
  return w.u;
}

// async global->LDS, 16B per lane; LDS dest = wave-uniform base + lane*16.
__device__ __forceinline__ void gload16(const bf16* g, bf16* l) {
  __builtin_amdgcn_global_load_lds(
      (const __attribute__((address_space(1))) void*)(g),
      (__attribute__((address_space(3))) void*)(l), 16, 0, 0);
}

// raw barrier with compiler memory fences (keep LDS ops from crossing)
__device__ __forceinline__ void barrier_raw() {
  asm volatile("" ::: "memory");
  __builtin_amdgcn_s_barrier();
  asm volatile("" ::: "memory");
}

// barrier that orders LDS ops only (lgkmcnt) — does NOT drain vmcnt.
// Safe when global loads target registers (private), not LDS.
__device__ __forceinline__ void barrier_lgkm() {
  asm volatile("s_waitcnt lgkmcnt(0)" ::: "memory");
  __builtin_amdgcn_s_barrier();
  asm volatile("" ::: "memory");
}

// ---------------- fused cast + weight transposes --------------------------
// blocks 0..2047: x f32->bf16. 2048..2815: Wq/Wk/Wv -> WqkvT. 2816..3071: Wo.
__global__ __launch_bounds__(256) void prep_all(const float* __restrict__ x,
                                                const float* __restrict__ Wq,
                                                const float* __restrict__ Wk,
                                                const float* __restrict__ Wv,
                                                const float* __restrict__ Wo,
                                                bf16* __restrict__ xb,
                                                bf16* __restrict__ WqkvT,
                                                bf16* __restrict__ WoT) {
  __shared__ bf16 tile[64][80];
  int id = blockIdx.x;
  int t = threadIdx.x;
  if (id < 2048) {
    int i = id * 2048 + t * 8;
    float4 a = *(const float4*)(x + i);
    float4 b = *(const float4*)(x + i + 4);
    union { bf16 h[8]; bfrag v; } tmp;
    tmp.h[0] = __float2bfloat16(a.x); tmp.h[1] = __float2bfloat16(a.y);
    tmp.h[2] = __float2bfloat16(a.z); tmp.h[3] = __float2bfloat16(a.w);
    tmp.h[4] = __float2bfloat16(b.x); tmp.h[5] = __float2bfloat16(b.y);
    tmp.h[6] = __float2bfloat16(b.z); tmp.h[7] = __float2bfloat16(b.w);
    *(bfrag*)(xb + i) = tmp.v;
    return;
  }
  int wid = id - 2048;
  const float* src;
  bf16* dst;
  int srcld, dstld, r0, c0;
  if (wid < 768) {
    int w = wid >> 8, h = (wid >> 4) & 15;
    r0 = (wid & 15) * 64; c0 = 0;
    src = ((w == 0) ? Wq : (w == 1) ? Wk : Wv) + (long)h * 1024 * 64;
    dst = WqkvT + ((long)w * 1024 + h * 64) * 1024;
    srcld = 64; dstld = 1024;
  } else {
    int j = wid - 768;
    c0 = (j & 15) * 64; r0 = (j >> 4) * 64;
    src = Wo; dst = WoT;
    srcld = 1024; dstld = 1024;
  }
  int lr = t >> 3, lc = (t & 7) << 3;
#pragma unroll
  for (int p = 0; p < 2; ++p) {
    int r = lr + p * 32;
    const float* s = src + (long)(r0 + r) * srcld + c0 + lc;
    union { bf16 h8[8]; bfrag v; } tmp;
#pragma unroll
    for (int j = 0; j < 8; ++j) tmp.h8[j] = __float2bfloat16(s[j]);
    *(bfrag*)(&tile[r][lc]) = tmp.v;
  }
  __syncthreads();
#pragma unroll
  for (int p = 0; p < 2; ++p) {
    int c = lr + p * 32;
    union { bf16 h8[8]; bfrag v; } tmp;
#pragma unroll
    for (int j = 0; j < 8; ++j) tmp.h8[j] = tile[lc + j][c];
    *(bfrag*)(dst + (long)(c0 + c) * dstld + r0 + lc) = tmp.v;
  }
}

// ---------------- fused QKV GEMM: 256x192, BK=64, 8-phase counted-vmcnt ---
// (R20-proven.) C[4096][3072] = xb . WT^T. 16x16 = 256 blocks, 512 thr.
__global__ __launch_bounds__(512, 2) void gemm_qkv128(const bf16* __restrict__ xb,
                                                      const bf16* __restrict__ WT,
                                                      const float* __restrict__ bq,
                                                      const float* __restrict__ bk,
                                                      const float* __restrict__ bv,
                                                      bf16* __restrict__ Q,
                                                      bf16* __restrict__ K_,
                                                      bf16* __restrict__ Vt) {
  extern __shared__ bf16 lds[];
  int id = blockIdx.x;
  int xcd = id & 7, idx = id >> 3;
  int tile = xcd * 32 + idx;          // 256 = 16 mt x 16 nt, bijective
  int mt = tile & 15, nt = tile >> 4;
  int m0 = mt * 256, n0 = nt * 192;

  int t = threadIdx.x;
  int wave = t >> 6, lane = t & 63, quad = lane >> 4, col = lane & 15;
  int wm = wave >> 2, wn = wave & 3;

  int schunk = 8 * ((t & 7) ^ ((t >> 3) & 7));   // pre-swizzled source chunk
  const bf16* aSrc = xb + (long)(m0 + (t >> 3)) * 1024 + schunk;
  const bf16* bSrc = WT + (long)(n0 + (t >> 3)) * 1024 + schunk;
  int wv512 = wave * 512;                         // wave-uniform LDS sub-base

  int xoff0 = (quad * 8) ^ ((col & 7) << 3);
  const bf16* aRdB = lds + wm * 8192 + col * 64;
  const bf16* bRdB = lds + 32768 + (wn * 48 + col) * 64;

  f32x4 acc[8][3] = {};

#define STA(BUF, HALF, G, KS)                                                  \
  gload16(aSrc + (long)((HALF)*128 + (G)*64) * 1024 + (KS)*64,                 \
          lds + (BUF)*16384 + (HALF)*8192 + (G)*4096 + wv512)
#define STB(BUF, G, KS)                                                        \
  gload16(bSrc + (long)((G)*64) * 1024 + (KS)*64,                              \
          lds + 32768 + (BUF)*12288 + (G)*4096 + wv512)

#define PHASE(BUF, MH, KC, STAGES, VMW)                                        \
  {                                                                            \
    int xk = xoff0 ^ ((KC)*32);                                                \
    bfrag ra[4], rb[3];                                                        \
    _Pragma("unroll") for (int u = 0; u < 4; ++u)                              \
      ra[u] = *(const bfrag*)(aRdB + (BUF)*16384 + (MH)*4096 + u * 1024 + xk); \
    _Pragma("unroll") for (int c2 = 0; c2 < 3; ++c2)                           \
      rb[c2] = *(const bfrag*)(bRdB + (BUF)*12288 + c2 * 1024 + xk);           \
    STAGES;                                                                    \
    VMW;                                                                       \
    barrier_raw();                                                             \
    __builtin_amdgcn_s_setprio(1);                                             \
    _Pragma("unroll") for (int ni = 0; ni < 3; ++ni)                           \
      _Pragma("unroll") for (int mi2 = 0; mi2 < 4; ++mi2)                      \
        acc[(MH)*4 + mi2][ni] = MFMA16(ra[mi2], rb[ni], acc[(MH)*4 + mi2][ni]);\
    __builtin_amdgcn_s_setprio(0);                                             \
    barrier_raw();                                                             \
  }

#define VM2 asm volatile("s_waitcnt vmcnt(2)" ::: "memory")
#define NOVM

  STA(0, 0, 0, 0); STA(0, 1, 0, 0); STA(0, 0, 1, 0); STA(0, 1, 1, 0);
  STB(0, 0, 0); STB(0, 1, 0); STB(0, 2, 0);
  STA(1, 0, 0, 1); STA(1, 1, 0, 1);
  VM2;
  barrier_raw();

  for (int it = 0; it < 8; ++it) {
    int ksB = 2 * it + 1;
    int kA  = (it < 7) ? 2 * it + 2 : 14;
    int ksB2 = (it < 7) ? 2 * it + 3 : 15;
    PHASE(0, 0, 0, { STA(1, 0, 1, ksB); STA(1, 1, 1, ksB); }, NOVM);   // p1
    PHASE(0, 0, 1, { STB(1, 0, ksB); STB(1, 1, ksB); }, NOVM);         // p2
    PHASE(0, 1, 0, { STB(1, 2, ksB); }, NOVM);                         // p3
    PHASE(0, 1, 1, { STA(0, 0, 0, kA); STA(0, 1, 0, kA); }, VM2);      // p4
    PHASE(1, 0, 0, { STA(0, 0, 1, kA); STA(0, 1, 1, kA); }, NOVM);     // p5
    PHASE(1, 0, 1, { STB(0, 0, kA); STB(0, 1, kA); }, NOVM);           // p6
    PHASE(1, 1, 0, { STB(0, 2, kA); }, NOVM);                          // p7
    PHASE(1, 1, 1, { STA(1, 0, 0, ksB2); STA(1, 1, 0, ksB2); }, VM2);  // p8
  }
#undef PHASE
#undef STA
#undef STB
#undef VM2
#undef NOVM

  asm volatile("s_waitcnt vmcnt(0)" ::: "memory");
  barrier_raw();

  const float SC2 = 0.18033688f;    // (1/8)*log2(e) folded into Q
  int b = m0 >> 11, sbase = m0 & 2047;

  if (n0 < 1920) {
#pragma unroll
    for (int ni = 0; ni < 3; ++ni) {
      int n = wn * 48 + ni * 16 + col;
      int ng = n0 + n;
      int s01 = ng >> 10;
      float bvv = s01 ? bk[ng & 1023] : bq[ng & 1023];
      float qsv = s01 ? 1.0f : SC2;
#pragma unroll
      for (int mi = 0; mi < 8; ++mi) {
        int mrow = wm * 128 + mi * 16 + quad * 4;
#pragma unroll
        for (int r = 0; r < 4; ++r)
          lds[(mrow + r) * 200 + n] = __float2bfloat16((acc[mi][ni][r] + bvv) * qsv);
      }
    }
    barrier_raw();
    int row = t >> 1, half = t & 1;
#pragma unroll
    for (int s = 0; s < 12; ++s) {
      int cl = 96 * half + 8 * s;
      int ng = n0 + cl;
      int s01 = ng >> 10, within = ng & 1023;
      int h = within >> 6, d = within & 63;
      bf16* dst = s01 ? K_ : Q;
      *(bfrag*)(dst + ((long)((b << 4) + h) * 2048 + sbase + row) * 64 + d) =
          *(const bfrag*)(lds + row * 200 + cl);
    }
  } else if (n0 == 1920) {
#pragma unroll
    for (int ni = 0; ni < 3; ++ni) {
      int n = wn * 48 + ni * 16 + col;
      int ng = n0 + n;
      if (ng < 2048) {
        float bvv = bk[ng & 1023];
#pragma unroll
        for (int mi = 0; mi < 8; ++mi) {
          int mrow = wm * 128 + mi * 16 + quad * 4;
#pragma unroll
          for (int r = 0; r < 4; ++r)
            lds[(mrow + r) * 136 + n] = __float2bfloat16(acc[mi][ni][r] + bvv);
        }
      } else {
        int vn = n - 128;
        float bvv = bv[ng & 1023];
#pragma unroll
        for (int mi = 0; mi < 8; ++mi) {
          int m = wm * 128 + mi * 16 + quad * 4;
          union { unsigned u[2]; unsigned long long ull; } pkd;
          pkd.u[0] = pk2(acc[mi][ni][0] + bvv, acc[mi][ni][1] + bvv);
          pkd.u[1] = pk2(acc[mi][ni][2] + bvv, acc[mi][ni][3] + bvv);
          *(unsigned long long*)(lds + 34816 + vn * 264 + m) = pkd.ull;
        }
      }
    }
    barrier_raw();
#pragma unroll
    for (int p = 0; p < 8; ++p) {
      int u = p * 512 + t;
      int row = u >> 4, cl = (u & 15) * 8;
      int within = (n0 + cl) & 1023;
      int h = within >> 6, d = within & 63;
      *(bfrag*)(K_ + ((long)((b << 4) + h) * 2048 + sbase + row) * 64 + d) =
          *(const bfrag*)(lds + row * 136 + cl);
    }
#pragma unroll
    for (int p = 0; p < 4; ++p) {
      int u = p * 512 + t;
      int vn = u >> 5, seg = (u & 31) * 8;
      int within = (n0 + 128 + vn) & 1023;
      int h = within >> 6, d = within & 63;
      *(bfrag*)(Vt + ((long)((b << 4) + h) * 64 + d) * 2048 + sbase + seg) =
          *(const bfrag*)(lds + 34816 + vn * 264 + seg);
    }
  } else {
#pragma unroll
    for (int ni = 0; ni < 3; ++ni) {
      int n = wn * 48 + ni * 16 + col;
      int ng = n0 + n;
      float bvv = bv[ng & 1023];
#pragma unroll
      for (int mi = 0; mi < 8; ++mi) {
        int m = wm * 128 + mi * 16 + quad * 4;
        union { unsigned u[2]; unsigned long long ull; } pkd;
        pkd.u[0] = pk2(acc[mi][ni][0] + bvv, acc[mi][ni][1] + bvv);
        pkd.u[1] = pk2(acc[mi][ni][2] + bvv, acc[mi][ni][3] + bvv);
        *(unsigned long long*)(lds + n * 264 + m) = pkd.ull;
      }
    }
    barrier_raw();
#pragma unroll
    for (int p = 0; p < 12; ++p) {
      int u = p * 512 + t;
      int rn = u >> 5, seg = (u & 31) * 8;
      int within = (n0 + rn) & 1023;
      int h = within >> 6, d = within & 63;
      *(bfrag*)(Vt + ((long)((b << 4) + h) * 64 + d) * 2048 + sbase + seg) =
          *(const bfrag*)(lds + rn * 264 + seg);
    }
  }
}

// ---------------- out-projection: 128x64, BK=64, gload_lds dbuf -----------
__global__ __launch_bounds__(256) void gemm_out(const bf16* __restrict__ O,
                                                const bf16* __restrict__ Bt,
                                                float* __restrict__ Cf) {
  const int K = 1024;
  __shared__ bf16 As[2][128 * 64];
  __shared__ bf16 Bs[2][64 * 64];
  int id = blockIdx.x;
  int xcd = id & 7, sw = id >> 3;
  int m0 = ((xcd << 2) | (sw & 3)) * 128;
  int n0 = (sw >> 2) * 64;
  int t = threadIdx.x;
  int wave = t >> 6, lane = t & 63, quad = lane >> 4, col = lane & 15;
  int wr = (wave >> 1) * 64, wc = (wave & 1) * 32;
  f32x4 acc[2][4] = {};

  int schunk = 8 * ((t & 7) ^ ((t >> 3) & 7));
  int ob = m0 >> 11;
  const bf16* AsrcB = O + (long)ob * 2097152 + (long)((m0 & 2047) + (t >> 3)) * 64 + schunk;
  const bf16* BsrcB = Bt + (long)(n0 + (t >> 3)) * K + schunk;
  int wv = wave * 512;
  int xoff0 = (quad * 8) ^ ((col & 7) << 3);

#define OUT_STAGE(bi, k0n)                                                 \
  {                                                                        \
    long ko = ((long)((k0n) >> 6)) * 131072;                               \
    _Pragma("unroll") for (int i = 0; i < 4; ++i)                          \
      gload16(AsrcB + ko + (long)(32 * i) * 64, &As[bi][i * 2048 + wv]);   \
    _Pragma("unroll") for (int i = 0; i < 2; ++i)                          \
      gload16(BsrcB + (k0n) + (long)(32 * i) * K, &Bs[bi][i * 2048 + wv]); \
  }

  OUT_STAGE(0, 0);
  __syncthreads();
  for (int k0 = 0; k0 < K; k0 += 64) {
    int cur = (k0 >> 6) & 1;
    if (k0 + 64 < K) OUT_STAGE(cur ^ 1, k0 + 64);
#pragma unroll
    for (int kc = 0; kc < 2; ++kc) {
      int xk = xoff0 ^ (kc * 32);
      bfrag ra[4], rb[2];
#pragma unroll
      for (int i = 0; i < 4; ++i)
        ra[i] = *(const bfrag*)(&As[cur][(wr + 16 * i + col) * 64 + xk]);
#pragma unroll
      for (int c = 0; c < 2; ++c)
        rb[c] = *(const bfrag*)(&Bs[cur][(wc + 16 * c + col) * 64 + xk]);
#pragma unroll
      for (int c = 0; c < 2; ++c)
#pragma unroll
        for (int i = 0; i < 4; ++i) acc[c][i] = MFMA16(ra[i], rb[c], acc[c][i]);
    }
    __syncthreads();
  }
#undef OUT_STAGE

#pragma unroll
  for (int c = 0; c < 2; ++c) {
    int n = n0 + wc + 16 * c + col;
#pragma unroll
    for (int i = 0; i < 4; ++i)
#pragma unroll
      for (int r = 0; r < 4; ++r) {
        int m = m0 + wr + 16 * i + quad * 4 + r;
        Cf[(long)m * 1024 + n] = acc[c][i][r];
      }
  }
}

// ---------------- flash attention: S^T dataflow, lgkm-only barriers -------
// R20 structure; in-loop barriers are lgkmcnt-only (staging is reg-based, so
// the vmcnt drain in __syncthreads was pure stall — prefetch now spans the
// compute phase).
__global__ __launch_bounds__(256) void attn_kernel(const bf16* __restrict__ Q,
                                                   const bf16* __restrict__ K_,
                                                   const bf16* __restrict__ Vt,
                                                   bf16* __restrict__ O) {
  int id = blockIdx.x;             // 1024 blocks
  int xcd = id & 7, jj = id >> 3;
  int qt = 31 - (jj >> 2);         // LPT
  int bh = ((jj & 3) << 3) | xcd;  // 4 bh per XCD

  __shared__ bf16 Ks[128][72];     // [j][d]; f32 Osc[64][68] overlay in epilogue
  __shared__ bf16 Vs[64][136];     // [d][j]; Lsc + Of overlay in epilogue

  int t = threadIdx.x, wave = t >> 6, lane = t & 63;
  int qh = wave >> 1, jh = wave & 1, hi = lane >> 5, l5 = lane & 31;

  int krow = t >> 3, kg = (t & 7) * 8;
  int vrow = t >> 4, vg = (t & 15) * 8;
  const bf16* KuBase = K_ + (long)bh * 2048 * 64;
  const bf16* VuBase = Vt + (long)bh * 64 * 2048;
  int kL = krow * 64 + kg;         // lane-const
  int vL = vrow * 2048 + vg;       // lane-const

  int q0 = qt * 64;
  int nj = (qt >> 1) + 1;
  int qi = q0 + 32 * qh + l5;      // this lane's global q index

  bfrag qa[4];
  const bf16* qp = Q + ((long)bh * 2048 + q0 + 32 * qh + l5) * 64 + hi * 8;
#pragma unroll
  for (int kd = 0; kd < 4; ++kd) qa[kd] = *(const bfrag*)(qp + kd * 16);

  f32x16 o0, o1;                   // O^T partials: rows d / d+32, col q
  float lsum = 0.f;                // per-lane: sum over this wave's j-half
#pragma unroll
  for (int r = 0; r < 16; ++r) { o0[r] = 0.f; o1[r] = 0.f; }

  // prefetch j-tile 0 (both K and V)
  bfrag kreg[4], vreg[4];
#pragma unroll
  for (int i = 0; i < 4; ++i) {
    kreg[i] = *(const bfrag*)(KuBase + kL + i * 2048);
    vreg[i] = *(const bfrag*)(VuBase + vL + i * 32768);
  }

  for (int jt = 0; jt < nj; ++jt) {
    int j0 = jt * 128;
    barrier_lgkm();                // prev iter's Ks/Vs reads complete (regs)
#pragma unroll
    for (int i = 0; i < 4; ++i) {
      *(bfrag*)(&Ks[krow + 32 * i][kg]) = kreg[i];
      *(bfrag*)(&Vs[vrow + 16 * i][vg]) = vreg[i];
    }
    int jn = (jt + 1 < nj) ? j0 + 128 : j0;       // uniform
    const bf16* kp = KuBase + (long)jn * 64;      // uniform base
    const bf16* vp = VuBase + jn;                 // uniform base
#pragma unroll
    for (int i = 0; i < 4; ++i) {
      kreg[i] = *(const bfrag*)(kp + kL + i * 2048);
      vreg[i] = *(const bfrag*)(vp + vL + i * 32768);
    }
    barrier_lgkm();                // ds_writes visible; prefetch stays in flight

    bool lastT = (jt == nj - 1);
    // even qt: last tile's jh==1 half (j in [q0+64,q0+128)) is fully masked.
    if (lastT && jh == 1 && ((qt & 1) == 0)) continue;

    // S^T: per wave 64j (own half) x 32q. A = K rows, B = Q rows.
    f32x16 s0, s1;
#pragma unroll
    for (int r = 0; r < 16; ++r) { s0[r] = 0.f; s1[r] = 0.f; }
    __builtin_amdgcn_s_setprio(1);
#pragma unroll
    for (int kd = 0; kd < 4; ++kd) {
      bfrag ka0 = *(const bfrag*)(&Ks[jh * 64 + l5][kd * 16 + hi * 8]);
      bfrag ka1 = *(const bfrag*)(&Ks[jh * 64 + 32 + l5][kd * 16 + hi * 8]);
      s0 = MFMA32(ka0, qa[kd], s0);
      s1 = MFMA32(ka1, qa[kd], s1);
    }
    __builtin_amdgcn_s_setprio(0);

    // softmax in-register; pack P^T bf16 groups (g[jb][0..3] = r0-3,4-7,8-11,12-15)
    unsigned g[2][4][2];
#pragma unroll
    for (int jb = 0; jb < 2; ++jb) {
      float pv[16];
      float ls = 0.f;
#pragma unroll
      for (int r = 0; r < 16; ++r) {
        int jl = (r & 3) + 8 * (r >> 2) + 4 * hi;        // j within 32-block
        int j = j0 + jh * 64 + jb * 32 + jl;
        float sv = jb ? s1[r] : s0[r];
        float p = __builtin_amdgcn_exp2f(sv);
        if (lastT) p = (j <= qi) ? p : 0.f;
        ls += p;
        pv[r] = p;
      }
      lsum += ls;
#pragma unroll
      for (int gg = 0; gg < 4; ++gg) {
        g[jb][gg][0] = pk2(pv[4 * gg], pv[4 * gg + 1]);
        g[jb][gg][1] = pk2(pv[4 * gg + 2], pv[4 * gg + 3]);
      }
    }

    // PV: O^T += V^T * P^T over own j-half
    __builtin_amdgcn_s_setprio(1);
#pragma unroll
    for (int jb = 0; jb < 2; ++jb) {
#pragma unroll
      for (int c = 0; c < 2; ++c) {
        unsigned a0 = g[jb][2 * c][0], a1 = g[jb][2 * c][1];
        unsigned b0 = g[jb][2 * c + 1][0], b1 = g[jb][2 * c + 1][1];
        asm("v_permlane32_swap_b32 %0, %1" : "+v"(a0), "+v"(b0));
        asm("v_permlane32_swap_b32 %0, %1" : "+v"(a1), "+v"(b1));
        union { unsigned u[4]; bfrag f; } pf;
        pf.u[0] = a0;
        pf.u[1] = a1;
        pf.u[2] = b0;
        pf.u[3] = b1;
        int kk = jh * 64 + jb * 32 + c * 16 + hi * 8;
        bfrag av0 = *(const bfrag*)(&Vs[l5][kk]);
        bfrag av1 = *(const bfrag*)(&Vs[32 + l5][kk]);
        o0 = MFMA32(av0, pf.f, o0);
        o1 = MFMA32(av1, pf.f, o1);
      }
    }
    __builtin_amdgcn_s_setprio(0);
  }

  // combine hi-halves of lsum (same q, different j-sets)
  lsum += __shfl_xor(lsum, 32, 64);

  __syncthreads();   // full drain (dummy tail prefetch) + overlay scratch
  float* Osc = (float*)&Ks[0][0];                    // [64 q][68 d]
  float* Lsc = (float*)&Vs[0][0];                    // [64 q]
  bf16* Of = (bf16*)((char*)&Vs[0][0] + 512);        // [64 q][72 d]
  int q = 32 * qh + l5;
  if (jh == 1) {
#pragma unroll
    for (int r = 0; r < 16; ++r) {
      int d = (r & 3) + 8 * (r >> 2) + 4 * hi;
      Osc[q * 68 + d] = o0[r];
      Osc[q * 68 + 32 + d] = o1[r];
    }
    if (hi == 0) Lsc[q] = lsum;
  }
  __syncthreads();
  if (jh == 0) {
    float inv = 1.f / (lsum + Lsc[q]);
#pragma unroll
    for (int r = 0; r < 16; ++r) {
      int d = (r & 3) + 8 * (r >> 2) + 4 * hi;
      Of[q * 72 + d] = __float2bfloat16((o0[r] + Osc[q * 68 + d]) * inv);
      Of[q * 72 + 32 + d] = __float2bfloat16((o1[r] + Osc[q * 68 + 32 + d]) * inv);
    }
  }
  __syncthreads();
  int row = t >> 2, off = (t & 3) * 16;
  bf16* po = O + ((long)bh * 2048 + q0 + row) * 64 + off;
  *(bfrag*)(po) = *(const bfrag*)(&Of[row * 72 + off]);
  *(bfrag*)(po + 8) = *(const bfrag*)(&Of[row * 72 + off + 8]);
}

extern "C" void kernel_launch(void* const* d_in, const int* in_sizes, int n_in,
                              void* d_out, int out_size, void* d_ws, size_t ws_size,
                              hipStream_t stream) {
  const float* x  = (const float*)d_in[0];
  const float* Wq = (const float*)d_in[1];
  const float* bq = (const float*)d_in[2];
  const float* Wk = (const float*)d_in[3];
  const float* bk = (const float*)d_in[4];
  const float* Wv = (const float*)d_in[5];
  const float* bv = (const float*)d_in[6];
  const float* Wo = (const float*)d_in[7];
  float* out = (float*)d_out;

  bf16* ws = (bf16*)d_ws;
  const long MB1 = 1 << 20;
  bf16* WqkvT = ws + 0 * MB1;    // [3072][1024]
  bf16* WoT   = ws + 3 * MB1;
  bf16* Q     = ws + 4 * MB1;    // [b][h][s][d]
  bf16* K_    = ws + 8 * MB1;    // [b][h][s][d]
  bf16* Vt    = ws + 12 * MB1;   // [b][h][d][s]
  bf16* O     = ws + 16 * MB1;   // [b][h][s][d]
  bf16* xb    = ws + 20 * MB1;

  prep_all<<<3072, 256, 0, stream>>>(x, Wq, Wk, Wv, Wo, xb, WqkvT, WoT);
  gemm_qkv128<<<256, 512, 114688, stream>>>(xb, WqkvT, bq, bk, bv, Q, K_, Vt);
  attn_kernel<<<1024, 256, 0, stream>>>(Q, K_, Vt, O);
  gemm_out<<<512, 256, 0, stream>>>(O, WoT, out);
}